// Round 7
// baseline (392.519 us; speedup 1.0000x reference)
//
#include <hip/hip_runtime.h>
#include <hip/hip_bf16.h>

// Problem constants
constexpr int Bb = 8, Ll = 2048, Ww = 1024;
constexpr int BL = Bb * Ll;              // 16384

typedef short bf16x8 __attribute__((ext_vector_type(8)));
typedef float f32x4  __attribute__((ext_vector_type(4)));

// ---------- bf16 helpers ----------
__device__ inline unsigned short f2bf(float f) {
    union { float f; unsigned u; } v; v.f = f;
    unsigned u = v.u;
    unsigned r = (u + 0x7fffu + ((u >> 16) & 1u)) >> 16;
    return (unsigned short)r;
}
__device__ inline float bf2f(unsigned short h) {
    union { unsigned u; float f; } v; v.u = ((unsigned)h) << 16;
    return v.f;
}
// lerp two packed bf16 pairs -> packed bf16 pair
__device__ inline unsigned lerp_pair(unsigned pa, unsigned pb, float w0, float w1) {
    union { unsigned u; float f; } alo, ahi, blo, bhi;
    alo.u = pa << 16;  ahi.u = pa & 0xffff0000u;
    blo.u = pb << 16;  bhi.u = pb & 0xffff0000u;
    float hlo = w0 * alo.f + w1 * blo.f;
    float hhi = w0 * ahi.f + w1 * bhi.f;
    union { __hip_bfloat162 h2; unsigned u; } r;
    r.h2 = __float22bfloat162_rn(float2{hlo, hhi});
    return r.u;
}

// ---------- async global->LDS, 16B per lane ----------
__device__ inline void gl_lds16(const unsigned short* g, unsigned short* l) {
    __builtin_amdgcn_global_load_lds(
        (const __attribute__((address_space(1))) unsigned int*)g,
        (__attribute__((address_space(3))) unsigned int*)l, 16, 0, 0);
}

// ---------- kernel 1: fused prep = offsets (blocks 0..4095) + wconv (4096..4255)
//                      + mask dtype probe (4256..4271) ----------
__global__ __launch_bounds__(256) void prep_kernel(
    const float* __restrict__ x, const float* __restrict__ w_off, const float* __restrict__ b_off,
    const float* __restrict__ conv_w, const void* __restrict__ mraw,
    unsigned short* __restrict__ x_bf, float4* __restrict__ pk,
    unsigned short* __restrict__ w_t, int* __restrict__ flags)
{
    const int blk = blockIdx.x;
    const int tid = threadIdx.x;
    if (blk < 4096) {
        // ---- offsets + x -> bf16 (one wave per row) ----
        const int wave = tid >> 6, lane = tid & 63;
        const int bl = blk * 4 + wave;
        const int l = bl & (Ll - 1);
        const int c0 = lane * 16;

        const float* xr = x + (size_t)bl * Ww + c0;
        float4 v0 = *(const float4*)(xr + 0);
        float4 v1 = *(const float4*)(xr + 4);
        float4 v2 = *(const float4*)(xr + 8);
        float4 v3 = *(const float4*)(xr + 12);
        float xv[16] = { v0.x,v0.y,v0.z,v0.w, v1.x,v1.y,v1.z,v1.w,
                         v2.x,v2.y,v2.z,v2.w, v3.x,v3.y,v3.z,v3.w };

        uint4 pa, pb;
        unsigned* pu = (unsigned*)&pa;
        #pragma unroll
        for (int j = 0; j < 4; j++) pu[j] = (unsigned)f2bf(xv[j*2]) | ((unsigned)f2bf(xv[j*2+1]) << 16);
        pu = (unsigned*)&pb;
        #pragma unroll
        for (int j = 0; j < 4; j++) pu[j] = (unsigned)f2bf(xv[8+j*2]) | ((unsigned)f2bf(xv[8+j*2+1]) << 16);
        *(uint4*)&x_bf[(size_t)bl * Ww + c0]     = pa;
        *(uint4*)&x_bf[(size_t)bl * Ww + c0 + 8] = pb;

        float acc[5] = {0.f, 0.f, 0.f, 0.f, 0.f};
        const float* wp = w_off + (size_t)c0 * 5;
        #pragma unroll
        for (int j = 0; j < 16; j++) {
            #pragma unroll
            for (int k = 0; k < 5; k++) acc[k] += xv[j] * wp[j * 5 + k];
        }
        #pragma unroll
        for (int k = 0; k < 5; k++)
            #pragma unroll
            for (int off = 32; off; off >>= 1) acc[k] += __shfl_xor(acc[k], off);

        if (lane < 5) {
            float s = (lane == 0) ? acc[0] : (lane == 1) ? acc[1] : (lane == 2) ? acc[2]
                    : (lane == 3) ? acc[3] : acc[4];
            s += b_off[lane];
            float offv = tanhf(s) * 2.0f;
            float pos = (float)l + (float)(lane - 2) + offv;
            float p0 = floorf(pos);
            float frac = pos - p0;
            int i0 = (int)p0;
            int i1 = i0 + 1;
            int ok0 = (i0 >= 0) && (i0 < Ll);
            int ok1 = (i1 >= 0) && (i1 < Ll);
            float4 pkv;
            pkv.x = __int_as_float(min(max(i0, 0), Ll - 1));
            pkv.y = __int_as_float(min(max(i1, 0), Ll - 1));
            pkv.z = ok0 ? (1.0f - frac) : 0.0f;
            pkv.w = ok1 ? frac : 0.0f;
            pk[bl * 5 + lane] = pkv;
        }
    } else if (blk < 4256) {
        // ---- conv_w fp32 [g][o][c][k] -> pre-tiled swizzled bf16 images ----
        const int bb = blk - 4096;
        const int gnt = bb >> 2;               // 0..39 = g*20+nt
        const int part = bb & 3;
        const int g = gnt / 20, nt = gnt % 20;
        const int k = nt >> 2, o0 = (nt & 3) * 128;
        #pragma unroll
        for (int it = 0; it < 8; it++) {
            int chunk = part * 2048 + it * 256 + tid;    // 0..8191 per (g,nt)
            int r = chunk >> 6;
            int cq = chunk & 63;
            int cs = cq >> 2, q = cq & 3;
            int o = o0 + r;
            int c0 = cs * 32 + q * 8;
            const float* src = conv_w + (((size_t)(g * 512 + o) * 512 + c0) * 5 + k);
            ushort4 lo, hi;
            lo.x = f2bf(src[0]);  lo.y = f2bf(src[5]);  lo.z = f2bf(src[10]); lo.w = f2bf(src[15]);
            hi.x = f2bf(src[20]); hi.y = f2bf(src[25]); hi.z = f2bf(src[30]); hi.w = f2bf(src[35]);
            int dst16 = (gnt * 16 + cs) * 512 + r * 4 + (q ^ (r & 3));
            *(ushort4*)&w_t[(size_t)dst16 * 8]     = lo;
            *(ushort4*)&w_t[(size_t)dst16 * 8 + 4] = hi;
        }
    } else {
        // ---- mask dtype probe ----
        const unsigned char* mb = (const unsigned char*)mraw;
        const unsigned* mw = (const unsigned*)mraw;
        int gid = (blk - 4256) * 256 + tid;     // 4096 threads
        int nonint = 0, notf = 0, hasf = 0;
        for (int i = gid; i < BL; i += 4096) { if ((i & 3) && mb[i]) nonint = 1; }
        for (int i = gid; i < BL / 4; i += 4096) {
            unsigned w = mw[i];
            if (w == 0x3f800000u) hasf = 1; else if (w) notf = 1;
        }
        if (nonint) atomicOr(&flags[0], 1);
        if (notf)   atomicOr(&flags[1], 1);
        if (hasf)   atomicOr(&flags[2], 1);
    }
}

// ---------- kernel 2: fused deform GEMM -> h. Block = 64 rows x 256 cols. ----------
// grid (mt=256, nhalf=2, g=2) = 1024 blocks = 4/CU for latency hiding.
// A fragments lerped in registers from x_bf; B ping-pong global_load_lds images.
__global__ __launch_bounds__(256, 4) void gemm_kernel(
    const unsigned short* __restrict__ x_bf, const unsigned short* __restrict__ w_t,
    const float4* __restrict__ pk, const float* __restrict__ conv_b,
    unsigned short* __restrict__ h)
{
    __shared__ unsigned short Bs[2][2 * 4096];   // 2 x (2 images x 8KB) = 32 KB
    const int tid = threadIdx.x;
    const int mt = blockIdx.x;            // 0..255 (64-row tiles)
    const int nhalf = blockIdx.y;         // 0..1
    const int g = blockIdx.z;             // 0..1
    const int b = mt >> 5;
    const int lane = tid & 63, wave = tid >> 6;
    const int wr = (wave >> 1) * 32;      // row group: 0 or 32
    const int imgsel = wave & 1;          // 128-col half within the 256
    const int l15 = lane & 15, l4 = lane >> 4;
    const int sw = (l4 ^ (l15 & 3)) * 8;

    // preload B chunk for it=0 (k=0, cs=0): images nt0, nt0+1
    {
        const int nt0 = nhalf * 2;
        const unsigned short* W0 = w_t + ((size_t)((g * 20 + nt0) * 16 + 0)) * 4096;
        const unsigned short* W1 = w_t + ((size_t)((g * 20 + nt0 + 1) * 16 + 0)) * 4096;
        gl_lds16(W0 + tid * 8,        &Bs[0][tid * 8]);
        gl_lds16(W0 + 2048 + tid * 8, &Bs[0][2048 + tid * 8]);
        gl_lds16(W1 + tid * 8,        &Bs[0][4096 + tid * 8]);
        gl_lds16(W1 + 2048 + tid * 8, &Bs[0][4096 + 2048 + tid * 8]);
    }
    __syncthreads();

    f32x4 acc[2][8];
    #pragma unroll
    for (int i = 0; i < 2; i++)
        #pragma unroll
        for (int j = 0; j < 8; j++) acc[i][j] = (f32x4){0.f, 0.f, 0.f, 0.f};

    int buf = 0;
    for (int k = 0; k < 5; ++k) {
        // per-k row metadata (2 row-frags per wave)
        unsigned off0[2], off1[2];
        float w0r[2], w1r[2];
        #pragma unroll
        for (int i = 0; i < 2; i++) {
            const int bl = mt * 64 + wr + i * 16 + l15;
            float4 pkv = pk[bl * 5 + k];
            const int i0 = __float_as_int(pkv.x), i1 = __float_as_int(pkv.y);
            off0[i] = (unsigned)(((b << 11) + i0) * Ww + g * 512);
            off1[i] = (unsigned)(((b << 11) + i1) * Ww + g * 512);
            w0r[i] = pkv.z; w1r[i] = pkv.w;
        }
        for (int cs = 0; cs < 16; ++cs) {
            const int it = k * 16 + cs;
            if (it < 79) {                       // prefetch next B chunk
                const int it2 = it + 1;
                const int k2 = it2 >> 4, cs2 = it2 & 15;
                const int nt0 = k2 * 4 + nhalf * 2;
                const unsigned short* W0 = w_t + ((size_t)((g * 20 + nt0) * 16 + cs2)) * 4096;
                const unsigned short* W1 = w_t + ((size_t)((g * 20 + nt0 + 1) * 16 + cs2)) * 4096;
                gl_lds16(W0 + tid * 8,        &Bs[buf ^ 1][tid * 8]);
                gl_lds16(W0 + 2048 + tid * 8, &Bs[buf ^ 1][2048 + tid * 8]);
                gl_lds16(W1 + tid * 8,        &Bs[buf ^ 1][4096 + tid * 8]);
                gl_lds16(W1 + 2048 + tid * 8, &Bs[buf ^ 1][4096 + 2048 + tid * 8]);
            }
            // build A fragments in registers (deform lerp)
            const int ch0 = cs * 32 + l4 * 8;
            bf16x8 af[2];
            #pragma unroll
            for (int i = 0; i < 2; i++) {
                const uint4 ua = *(const uint4*)(x_bf + off0[i] + ch0);
                const uint4 ub = *(const uint4*)(x_bf + off1[i] + ch0);
                union { unsigned u[4]; bf16x8 v; } fa;
                fa.u[0] = lerp_pair(ua.x, ub.x, w0r[i], w1r[i]);
                fa.u[1] = lerp_pair(ua.y, ub.y, w0r[i], w1r[i]);
                fa.u[2] = lerp_pair(ua.z, ub.z, w0r[i], w1r[i]);
                fa.u[3] = lerp_pair(ua.w, ub.w, w0r[i], w1r[i]);
                af[i] = fa.v;
            }
            // B fragments from LDS image
            bf16x8 bfr[8];
            #pragma unroll
            for (int j = 0; j < 8; j++)
                bfr[j] = *(const bf16x8*)&Bs[buf][imgsel * 4096 + (j * 16 + l15) * 32 + sw];
            #pragma unroll
            for (int i = 0; i < 2; i++)
                #pragma unroll
                for (int j = 0; j < 8; j++)
                    acc[i][j] = __builtin_amdgcn_mfma_f32_16x16x32_bf16(af[i], bfr[j], acc[i][j], 0, 0, 0);
            __syncthreads();
            buf ^= 1;
        }
    }
    // epilogue: + conv_b, store h bf16
    #pragma unroll
    for (int j = 0; j < 8; j++) {
        const int col = g * 512 + nhalf * 256 + imgsel * 128 + j * 16 + l15;
        const float bias = conv_b[col];
        #pragma unroll
        for (int i = 0; i < 2; i++) {
            const int row0 = mt * 64 + wr + i * 16 + l4 * 4;
            #pragma unroll
            for (int rr = 0; rr < 4; rr++)
                h[(size_t)(row0 + rr) * Ww + col] = f2bf(acc[i][j][rr] + bias);
        }
    }
}

// ---------- kernel 3: LayerNorm + inline mask + pooled partials + lengths ----------
__global__ __launch_bounds__(256) void lnpool_kernel(
    const unsigned short* __restrict__ h, const float* __restrict__ gamma,
    const void* __restrict__ mraw, const int* __restrict__ flags,
    float* __restrict__ pooled, float* __restrict__ lengths)
{
    const int tid = threadIdx.x;
    const int wave = tid >> 6, lane = tid & 63;
    const int c0 = lane * 16;
    const int bl0 = blockIdx.x * 16 + wave * 4;
    const int b = bl0 >> 11;

    const unsigned char* mb = (const unsigned char*)mraw;
    const unsigned* mw = (const unsigned*)mraw;
    const int is_f32  = (!flags[1]) && flags[2];
    const int is_bool = (!is_f32) && flags[0];

    float g16[16];
    #pragma unroll
    for (int j = 0; j < 4; j++) {
        float4 gv = *(const float4*)(gamma + c0 + j * 4);
        g16[j*4+0] = gv.x; g16[j*4+1] = gv.y; g16[j*4+2] = gv.z; g16[j*4+3] = gv.w;
    }
    float pacc[16];
    #pragma unroll
    for (int j = 0; j < 16; j++) pacc[j] = 0.f;
    float cnt = 0.f;

    #pragma unroll
    for (int r = 0; r < 4; r++) {
        const int bl = bl0 + r;
        const int masked = is_bool ? (mb[bl] != 0) : (mw[bl] != 0u);
        const float m = masked ? 0.0f : 1.0f;
        cnt += m;
        const uint4 ha = *(const uint4*)(h + (size_t)bl * Ww + c0);
        const uint4 hb = *(const uint4*)(h + (size_t)bl * Ww + c0 + 8);
        float hf[16];
        const unsigned* pw = (const unsigned*)&ha;
        #pragma unroll
        for (int j = 0; j < 4; j++) {
            union { unsigned u; float f; } lo, hi;
            lo.u = pw[j] << 16; hi.u = pw[j] & 0xffff0000u;
            hf[j*2] = lo.f; hf[j*2+1] = hi.f;
        }
        pw = (const unsigned*)&hb;
        #pragma unroll
        for (int j = 0; j < 4; j++) {
            union { unsigned u; float f; } lo, hi;
            lo.u = pw[j] << 16; hi.u = pw[j] & 0xffff0000u;
            hf[8+j*2] = lo.f; hf[8+j*2+1] = hi.f;
        }
        float s1 = 0.f, s2 = 0.f;
        #pragma unroll
        for (int j = 0; j < 16; j++) { s1 += hf[j]; s2 += hf[j] * hf[j]; }
        #pragma unroll
        for (int off = 32; off; off >>= 1) {
            s1 += __shfl_xor(s1, off);
            s2 += __shfl_xor(s2, off);
        }
        const float mu = s1 * (1.0f / 1024.0f);
        const float var = s2 * (1.0f / 1024.0f) - mu * mu;
        const float rstd = rsqrtf(var + 1e-5f) * m;       // mask by multiply
        #pragma unroll
        for (int j = 0; j < 16; j++) pacc[j] += (hf[j] - mu) * rstd * g16[j];
    }
    if (lane == 0) atomicAdd(&lengths[b], cnt);
    __shared__ float spool[4][1024];
    #pragma unroll
    for (int j = 0; j < 4; j++)
        *(float4*)&spool[wave][c0 + j * 4] = *(float4*)&pacc[j * 4];
    __syncthreads();
    const int ch = tid * 4;
    float4 a = *(float4*)&spool[0][ch];
    float4 bq = *(float4*)&spool[1][ch];
    float4 cq = *(float4*)&spool[2][ch];
    float4 dq = *(float4*)&spool[3][ch];
    atomicAdd(&pooled[b * Ww + ch + 0], a.x + bq.x + cq.x + dq.x);
    atomicAdd(&pooled[b * Ww + ch + 1], a.y + bq.y + cq.y + dq.y);
    atomicAdd(&pooled[b * Ww + ch + 2], a.z + bq.z + cq.z + dq.z);
    atomicAdd(&pooled[b * Ww + ch + 3], a.w + bq.w + cq.w + dq.w);
}

// ---------- kernel 4: projection (beta folded: + sum(beta*proj)) ----------
__global__ void final_kernel(const float* __restrict__ pooled, const float* __restrict__ lengths,
                             const float* __restrict__ beta, const float* __restrict__ proj_w,
                             const float* __restrict__ proj_b, float* __restrict__ out)
{
    int b = blockIdx.x;
    int tid = threadIdx.x;
    float dotP = 0.f, dotB = 0.f;
    for (int c = tid; c < Ww; c += 256) {
        dotP += pooled[b * Ww + c] * proj_w[c];
        dotB += beta[c] * proj_w[c];
    }
    for (int off = 32; off; off >>= 1) {
        dotP += __shfl_down(dotP, off);
        dotB += __shfl_down(dotB, off);
    }
    __shared__ float rp[4], rb[4];
    int wave = tid >> 6, lane = tid & 63;
    if (lane == 0) { rp[wave] = dotP; rb[wave] = dotB; }
    __syncthreads();
    if (tid == 0) {
        float Pt = rp[0] + rp[1] + rp[2] + rp[3];
        float Bt = rb[0] + rb[1] + rb[2] + rb[3];
        out[b] = Pt / fmaxf(lengths[b], 1.0f) + Bt + proj_b[0];
    }
}

// ---------- workspace layout (bytes, 16B-aligned) ----------
// pooled  @        0  (32768)   \
// flags   @    32768  (16)       } one memset (32832 B)
// lengths @    32784  (32+pad)  /
// pk      @    32832  (1310720)
// w_t     @  1343552  (5242880)
// x_bf    @  6586432  (33554432)
// h       @ 40140864  (33554432)  -> total 73,695,296 B

extern "C" void kernel_launch(void* const* d_in, const int* in_sizes, int n_in,
                              void* d_out, int out_size, void* d_ws, size_t ws_size,
                              hipStream_t stream)
{
    const float* x      = (const float*)d_in[0];
    const void*  mask   = d_in[1];
    const float* w_off  = (const float*)d_in[2];
    const float* b_off  = (const float*)d_in[3];
    const float* conv_w = (const float*)d_in[4];
    const float* conv_b = (const float*)d_in[5];
    const float* gamma  = (const float*)d_in[6];
    const float* beta   = (const float*)d_in[7];
    const float* proj_w = (const float*)d_in[8];
    const float* proj_b = (const float*)d_in[9];
    float* out = (float*)d_out;

    char* ws = (char*)d_ws;
    float* pooled        = (float*)(ws + 0);
    int*   flags         = (int*)(ws + 32768);
    float* lengths       = (float*)(ws + 32784);
    float4* pk           = (float4*)(ws + 32832);
    unsigned short* w_t  = (unsigned short*)(ws + 1343552);
    unsigned short* x_bf = (unsigned short*)(ws + 6586432);
    unsigned short* h    = (unsigned short*)(ws + 40140864);

    hipMemsetAsync(pooled, 0, 32832, stream);
    prep_kernel<<<4272, 256, 0, stream>>>(x, w_off, b_off, conv_w, mask, x_bf, pk, w_t, flags);
    gemm_kernel<<<dim3(256, 2, 2), 256, 0, stream>>>(x_bf, w_t, pk, conv_b, h);
    lnpool_kernel<<<1024, 256, 0, stream>>>(h, gamma, mask, flags, pooled, lengths);
    final_kernel<<<8, 256, 0, stream>>>(pooled, lengths, beta, proj_w, proj_b, out);
}